// Round 1
// baseline (598.898 us; speedup 1.0000x reference)
//
#include <hip/hip_runtime.h>
#include <cstdint>

typedef __bf16 bf16;
typedef __attribute__((ext_vector_type(8))) __bf16 bf16x8;
typedef __attribute__((ext_vector_type(4))) __bf16 bf16x4;
typedef __attribute__((ext_vector_type(4))) float f32x4;

static __device__ __forceinline__ f32x4 mfma16(bf16x8 a, bf16x8 b, f32x4 c) {
    return __builtin_amdgcn_mfma_f32_16x16x32_bf16(a, b, c, 0, 0, 0);
}
static __device__ __forceinline__ bf16x4 cvt4(f32x4 v) {
    bf16x4 r; r[0]=(bf16)v[0]; r[1]=(bf16)v[1]; r[2]=(bf16)v[2]; r[3]=(bf16)v[3]; return r;
}

// ---------------------------------------------------------------------------
// K1: proj_in.  z_tok[(b,h,w)][o] = sum_c x[b,c,h,w] * Wi[o,c]   (bf16 out)
// Per-b GEMM M=128(o) x N=64(hw strip) x K=512(c).
// ---------------------------------------------------------------------------
__global__ __launch_bounds__(256) void k_proj_in(
    const float* __restrict__ x, const float* __restrict__ Wi, bf16* __restrict__ z)
{
    __shared__ bf16 As[128][72];   // Wi tile [o][k], pitch 72 (144B, 16B-aligned)
    __shared__ bf16 Bs[64][72];    // x tile transposed [n][k]
    const int tid = threadIdx.x;
    const int lane = tid & 63, w = tid >> 6;
    const int ll = lane & 15, lg = lane >> 4;
    const int b = blockIdx.x >> 9;
    const int n0 = (blockIdx.x & 511) * 64;
    const float* xb = x + (size_t)b * 512 * 32768;

    f32x4 acc[2][4];
    const f32x4 Z4 = {0.f,0.f,0.f,0.f};
    #pragma unroll
    for (int i=0;i<2;i++) { acc[i][0]=Z4; acc[i][1]=Z4; acc[i][2]=Z4; acc[i][3]=Z4; }

    for (int c0 = 0; c0 < 512; c0 += 64) {
        #pragma unroll
        for (int r = 0; r < 8; ++r) {       // stage A: 128x64 fp32 -> bf16
            int idx = r*256 + tid;
            int o = idx >> 4, cq = idx & 15;
            f32x4 v = *(const f32x4*)(Wi + (size_t)o*512 + c0 + cq*4);
            *(bf16x4*)&As[o][cq*4] = cvt4(v);
        }
        #pragma unroll
        for (int r = 0; r < 4; ++r) {       // stage B transposed: [n][k]
            int idx = r*256 + tid;
            int k = idx >> 4, nq = idx & 15;
            f32x4 v = *(const f32x4*)(xb + (size_t)(c0 + k)*32768 + n0 + nq*4);
            #pragma unroll
            for (int j=0;j<4;j++) Bs[nq*4+j][k] = (bf16)v[j];
        }
        __syncthreads();
        #pragma unroll
        for (int ks = 0; ks < 2; ++ks) {
            bf16x8 af[2], bfr[4];
            #pragma unroll
            for (int mt=0;mt<2;mt++) af[mt]  = *(const bf16x8*)&As[w*32+mt*16+ll][ks*32+lg*8];
            #pragma unroll
            for (int nt=0;nt<4;nt++) bfr[nt] = *(const bf16x8*)&Bs[nt*16+ll][ks*32+lg*8];
            #pragma unroll
            for (int mt=0;mt<2;mt++)
                #pragma unroll
                for (int nt=0;nt<4;nt++)
                    acc[mt][nt] = mfma16(af[mt], bfr[nt], acc[mt][nt]);
        }
        __syncthreads();
    }
    #pragma unroll
    for (int mt=0;mt<2;mt++)
      #pragma unroll
      for (int nt=0;nt<4;nt++) {
        int o0 = w*32 + mt*16 + lg*4;
        int token = b*32768 + n0 + nt*16 + ll;
        *(bf16x4*)&z[(size_t)token*128 + o0] = cvt4(acc[mt][nt]);
      }
}

// ---------------------------------------------------------------------------
// K2: fused LayerNorm + QKV projection.
// In: tokens [t][128] bf16 (seq-major, t = s*N + n).  Out:
//   Qb/Kb: [(s*4+h)*N + n][32] bf16        (dk-contiguous)
//   Vt:    [(s*4+h)*32 + dk][N] bf16       (n-contiguous; via swapped-operand mfma)
// ---------------------------------------------------------------------------
__global__ __launch_bounds__(256) void k_qkv(
    const bf16* __restrict__ zin, const float* __restrict__ lnw, const float* __restrict__ lnb,
    const float* __restrict__ Wq, const float* __restrict__ Wk, const float* __restrict__ Wv,
    bf16* __restrict__ Qb, bf16* __restrict__ Kb, bf16* __restrict__ Vt, int nshift)
{
    __shared__ bf16 xs[64][136];
    __shared__ bf16 wsm[128][136];
    const int tid = threadIdx.x;
    const int lane = tid & 63, w = tid >> 6;
    const int ll = lane & 15, lg = lane >> 4;
    const int t0 = blockIdx.x * 64;
    const int N = 1 << nshift;

    {   // stage LN(x) into xs (16 lanes per token)
        const int sub = tid & 15;
        float wv[8], bv[8];
        #pragma unroll
        for (int j=0;j<8;j++){ wv[j]=lnw[sub*8+j]; bv[j]=lnb[sub*8+j]; }
        #pragma unroll
        for (int r=0;r<4;r++){
            int tl = r*16 + (tid >> 4);
            bf16x8 v = *(const bf16x8*)&zin[(size_t)(t0+tl)*128 + sub*8];
            float f[8]; float sm=0.f, ssq=0.f;
            #pragma unroll
            for (int j=0;j<8;j++){ f[j]=(float)v[j]; sm+=f[j]; ssq+=f[j]*f[j]; }
            #pragma unroll
            for (int d=1; d<16; d<<=1){ sm += __shfl_xor(sm,d); ssq += __shfl_xor(ssq,d); }
            float mean = sm*(1.f/128.f);
            float var  = ssq*(1.f/128.f) - mean*mean;
            float rr = rsqrtf(var + 1e-5f);
            bf16x8 ov;
            #pragma unroll
            for (int j=0;j<8;j++) ov[j] = (bf16)((f[j]-mean)*rr*wv[j] + bv[j]);
            *(bf16x8*)&xs[tl][sub*8] = ov;
        }
    }

    const float* Wm[3] = {Wq, Wk, Wv};
    const f32x4 Z4 = {0.f,0.f,0.f,0.f};
    for (int m = 0; m < 3; ++m) {
        __syncthreads();
        #pragma unroll
        for (int r=0;r<16;r++){
            int idx = r*256 + tid;
            int o = idx >> 5, q = idx & 31;
            f32x4 v = *(const f32x4*)(Wm[m] + (size_t)o*128 + q*4);
            *(bf16x4*)&wsm[o][q*4] = cvt4(v);
        }
        __syncthreads();
        f32x4 acc[4][2];
        #pragma unroll
        for (int i=0;i<4;i++){ acc[i][0]=Z4; acc[i][1]=Z4; }
        #pragma unroll
        for (int ks=0; ks<4; ++ks){
            bf16x8 xa[4], wb[2];
            #pragma unroll
            for (int tt=0;tt<4;tt++) xa[tt] = *(const bf16x8*)&xs[tt*16+ll][ks*32+lg*8];
            #pragma unroll
            for (int ot=0;ot<2;ot++) wb[ot] = *(const bf16x8*)&wsm[w*32+ot*16+ll][ks*32+lg*8];
            if (m < 2) {
                #pragma unroll
                for (int tt=0;tt<4;tt++)
                    #pragma unroll
                    for (int ot=0;ot<2;ot++)
                        acc[tt][ot] = mfma16(xa[tt], wb[ot], acc[tt][ot]);   // D[token][o]
            } else {
                #pragma unroll
                for (int tt=0;tt<4;tt++)
                    #pragma unroll
                    for (int ot=0;ot<2;ot++)
                        acc[tt][ot] = mfma16(wb[ot], xa[tt], acc[tt][ot]);   // D[o][token]
            }
        }
        if (m < 2) {
            bf16* dst = (m==0) ? Qb : Kb;
            #pragma unroll
            for (int tt=0;tt<4;tt++)
              #pragma unroll
              for (int ot=0;ot<2;ot++)
                #pragma unroll
                for (int r=0;r<4;r++){
                    int token = t0 + tt*16 + lg*4 + r;
                    int sq = token >> nshift, n = token & (N-1);
                    int dk = ot*16 + ll;
                    dst[((size_t)(sq*4 + w)*N + n)*32 + dk] = (bf16)acc[tt][ot][r];
                }
        } else {
            #pragma unroll
            for (int tt=0;tt<4;tt++)
              #pragma unroll
              for (int ot=0;ot<2;ot++)
                #pragma unroll
                for (int r=0;r<4;r++){
                    int dk = ot*16 + lg*4 + r;
                    int token = t0 + tt*16 + ll;
                    int sq = token >> nshift, n = token & (N-1);
                    Vt[((size_t)(sq*4 + w)*32 + dk)*N + n] = (bf16)acc[tt][ot][r];
                }
        }
    }
}

// ---------------------------------------------------------------------------
// K3: attention per (seq, head). 4 waves split queries. Flash over 32-key strips.
// Output written with residual and the (b,x,y)->(b,y,x) token transpose.
// ---------------------------------------------------------------------------
template<int N>
__global__ __launch_bounds__(256) void k_attn(
    const bf16* __restrict__ Qb, const bf16* __restrict__ Kb, const bf16* __restrict__ Vt,
    const bf16* __restrict__ tin, bf16* __restrict__ tout, int spb_shift)
{
    constexpr int MT = N/64;                 // 16-row query tiles per wave
    __shared__ bf16 Ks[N][40];               // [key][dk]
    __shared__ bf16 Vs[32][N+8];             // [dk][key]
    __shared__ bf16 Ps[4][N/4][40];          // wave-private P repack buffer
    const int tid = threadIdx.x;
    const int lane = tid & 63, w = tid >> 6;
    const int ll = lane & 15, lg = lane >> 4;
    const int s = blockIdx.x >> 2, h = blockIdx.x & 3;
    const size_t base = (size_t)(s*4 + h) * N * 32;

    #pragma unroll
    for (int r=0;r<N/64;r++){
        int idx = r*256 + tid;
        int n = idx >> 2, c = idx & 3;
        *(bf16x8*)&Ks[n][c*8] = *(const bf16x8*)&Kb[base + (size_t)n*32 + c*8];
    }
    #pragma unroll
    for (int r=0;r<N/64;r++){
        int idx = r*256 + tid;
        int dd = idx / (N/8), nc = idx % (N/8);
        *(bf16x8*)&Vs[dd][nc*8] = *(const bf16x8*)&Vt[base + (size_t)dd*N + nc*8];
    }
    const int q0 = w*(N/4);
    bf16x8 qf[MT];
    #pragma unroll
    for (int mt=0;mt<MT;mt++)
        qf[mt] = *(const bf16x8*)&Qb[base + (size_t)(q0 + mt*16 + ll)*32 + lg*8];
    __syncthreads();

    const f32x4 Z4 = {0.f,0.f,0.f,0.f};
    const f32x4 M4 = {-1e30f,-1e30f,-1e30f,-1e30f};
    f32x4 O[MT][2], mq[MT], lq[MT];
    #pragma unroll
    for (int mt=0;mt<MT;mt++){ O[mt][0]=Z4; O[mt][1]=Z4; mq[mt]=M4; lq[mt]=Z4; }

    const float cs = 0.2550354f;   // log2(e) / sqrt(32)
    for (int kv = 0; kv < N; kv += 32) {
        bf16x8 kf0 = *(const bf16x8*)&Ks[kv + ll][lg*8];
        bf16x8 kf1 = *(const bf16x8*)&Ks[kv + 16 + ll][lg*8];
        #pragma unroll
        for (int mt=0;mt<MT;mt++){
            f32x4 s0 = mfma16(qf[mt], kf0, Z4);   // D[q][key]
            f32x4 s1 = mfma16(qf[mt], kf1, Z4);
            #pragma unroll
            for (int r=0;r<4;r++){
                float a = s0[r]*cs, bq = s1[r]*cs;
                float rm = fmaxf(a, bq);
                #pragma unroll
                for (int d=1; d<16; d<<=1) rm = fmaxf(rm, __shfl_xor(rm, d));
                float mo = mq[mt][r];
                float mn = fmaxf(mo, rm);
                float alpha = exp2f(mo - mn);
                mq[mt][r] = mn;
                float p0 = exp2f(a - mn), p1 = exp2f(bq - mn);
                float rs = p0 + p1;
                #pragma unroll
                for (int d=1; d<16; d<<=1) rs += __shfl_xor(rs, d);
                lq[mt][r] = lq[mt][r]*alpha + rs;
                O[mt][0][r] *= alpha;
                O[mt][1][r] *= alpha;
                int ql = mt*16 + lg*4 + r;
                Ps[w][ql][ll]    = (bf16)p0;
                Ps[w][ql][16+ll] = (bf16)p1;
            }
        }
        bf16x8 vf0 = *(const bf16x8*)&Vs[ll][kv + lg*8];
        bf16x8 vf1 = *(const bf16x8*)&Vs[16+ll][kv + lg*8];
        #pragma unroll
        for (int mt=0;mt<MT;mt++){
            bf16x8 pf = *(const bf16x8*)&Ps[w][mt*16 + ll][lg*8];
            O[mt][0] = mfma16(pf, vf0, O[mt][0]);
            O[mt][1] = mfma16(pf, vf1, O[mt][1]);
        }
    }
    const int spb_mask = (1 << spb_shift) - 1;
    #pragma unroll
    for (int mt=0;mt<MT;mt++){
        #pragma unroll
        for (int r=0;r<4;r++){
            float inv = 1.f / lq[mt][r];
            int q = q0 + mt*16 + lg*4 + r;
            size_t ti = ((size_t)(s*N + q))*128 + h*32;
            size_t to = ((size_t)((((s >> spb_shift)*N + q) << spb_shift) + (s & spb_mask)))*128 + h*32;
            #pragma unroll
            for (int dt=0; dt<2; ++dt){
                int dout = dt*16 + ll;
                float val = O[mt][dt][r]*inv + (float)tin[ti + dout];
                tout[to + dout] = (bf16)val;
            }
        }
    }
}

// ---------------------------------------------------------------------------
// K4a: proj_out GEMM, partial GroupNorm sums only (no store of the big tensor).
// ---------------------------------------------------------------------------
__global__ __launch_bounds__(256) void k_gnsum(
    const bf16* __restrict__ f, const float* __restrict__ Wo, float* __restrict__ part)
{
    __shared__ bf16 As[128][136];
    __shared__ bf16 Bs[64][136];
    const int tid = threadIdx.x;
    const int lane = tid & 63, w = tid >> 6;
    const int ll = lane & 15, lg = lane >> 4;
    const int b  = blockIdx.x >> 11;
    const int ms = (blockIdx.x >> 9) & 3;
    const int ns = blockIdx.x & 511;
    const int n0 = ns*64, o0 = ms*128;

    #pragma unroll
    for (int r=0;r<16;r++){
        int idx = r*256 + tid;
        int o = idx >> 5, q = idx & 31;
        f32x4 v = *(const f32x4*)(Wo + (size_t)(o0+o)*128 + q*4);
        *(bf16x4*)&As[o][q*4] = cvt4(v);
    }
    #pragma unroll
    for (int r=0;r<4;r++){
        int idx = r*256 + tid;
        int nl = idx >> 4, ch = idx & 15;
        *(bf16x8*)&Bs[nl][ch*8] = *(const bf16x8*)&f[(size_t)(b*32768 + n0 + nl)*128 + ch*8];
    }
    __syncthreads();
    const f32x4 Z4 = {0.f,0.f,0.f,0.f};
    f32x4 acc[2][4];
    #pragma unroll
    for (int i=0;i<2;i++){ acc[i][0]=Z4; acc[i][1]=Z4; acc[i][2]=Z4; acc[i][3]=Z4; }
    #pragma unroll
    for (int ks=0;ks<4;ks++){
        bf16x8 af[2], bfr[4];
        #pragma unroll
        for (int mt=0;mt<2;mt++) af[mt]  = *(const bf16x8*)&As[w*32+mt*16+ll][ks*32+lg*8];
        #pragma unroll
        for (int nt=0;nt<4;nt++) bfr[nt] = *(const bf16x8*)&Bs[nt*16+ll][ks*32+lg*8];
        #pragma unroll
        for (int mt=0;mt<2;mt++)
            #pragma unroll
            for (int nt=0;nt<4;nt++)
                acc[mt][nt] = mfma16(af[mt], bfr[nt], acc[mt][nt]);
    }
    #pragma unroll
    for (int mt=0;mt<2;mt++){
        float ps=0.f, pss=0.f;
        #pragma unroll
        for (int nt=0;nt<4;nt++)
            #pragma unroll
            for (int r=0;r<4;r++){ float v = acc[mt][nt][r]; ps += v; pss += v*v; }
        #pragma unroll
        for (int d=1; d<64; d<<=1){ ps += __shfl_xor(ps,d); pss += __shfl_xor(pss,d); }
        if (lane == 0){
            int g = ms*8 + w*2 + mt;
            size_t pi = ((size_t)(b*32+g)*512 + ns)*2;
            part[pi] = ps; part[pi+1] = pss;
        }
    }
}

// K4b: reduce partials -> mean, rstd per (b, group)
__global__ __launch_bounds__(256) void k_gnstat(
    const float* __restrict__ part, float* __restrict__ stats)
{
    const int bg = blockIdx.x;
    float s = 0.f, ss = 0.f;
    for (int i = threadIdx.x; i < 512; i += 256) {
        s  += part[((size_t)bg*512 + i)*2];
        ss += part[((size_t)bg*512 + i)*2 + 1];
    }
    #pragma unroll
    for (int d=1; d<64; d<<=1){ s += __shfl_xor(s,d); ss += __shfl_xor(ss,d); }
    __shared__ float sh[8];
    const int w = threadIdx.x >> 6;
    if ((threadIdx.x & 63) == 0) { sh[w*2] = s; sh[w*2+1] = ss; }
    __syncthreads();
    if (threadIdx.x == 0) {
        float S = sh[0]+sh[2]+sh[4]+sh[6], SS = sh[1]+sh[3]+sh[5]+sh[7];
        float mean = S * (1.f/524288.f);
        float var  = SS * (1.f/524288.f) - mean*mean;
        stats[bg*2]   = mean;
        stats[bg*2+1] = rsqrtf(var + 1e-5f);
    }
}

// ---------------------------------------------------------------------------
// K5: proj_out GEMM again + GroupNorm apply + residual + fp32 store.
// ---------------------------------------------------------------------------
__global__ __launch_bounds__(256) void k_apply(
    const bf16* __restrict__ f, const float* __restrict__ Wo, const float* __restrict__ x,
    const float* __restrict__ stats, const float* __restrict__ gw, const float* __restrict__ gb,
    float* __restrict__ out)
{
    __shared__ bf16 As[128][136];
    __shared__ bf16 Bs[64][136];
    const int tid = threadIdx.x;
    const int lane = tid & 63, w = tid >> 6;
    const int ll = lane & 15, lg = lane >> 4;
    const int b  = blockIdx.x >> 11;
    const int ms = (blockIdx.x >> 9) & 3;
    const int ns = blockIdx.x & 511;
    const int n0 = ns*64, o0 = ms*128;

    #pragma unroll
    for (int r=0;r<16;r++){
        int idx = r*256 + tid;
        int o = idx >> 5, q = idx & 31;
        f32x4 v = *(const f32x4*)(Wo + (size_t)(o0+o)*128 + q*4);
        *(bf16x4*)&As[o][q*4] = cvt4(v);
    }
    #pragma unroll
    for (int r=0;r<4;r++){
        int idx = r*256 + tid;
        int nl = idx >> 4, ch = idx & 15;
        *(bf16x8*)&Bs[nl][ch*8] = *(const bf16x8*)&f[(size_t)(b*32768 + n0 + nl)*128 + ch*8];
    }
    __syncthreads();
    const f32x4 Z4 = {0.f,0.f,0.f,0.f};
    f32x4 acc[2][4];
    #pragma unroll
    for (int i=0;i<2;i++){ acc[i][0]=Z4; acc[i][1]=Z4; acc[i][2]=Z4; acc[i][3]=Z4; }
    #pragma unroll
    for (int ks=0;ks<4;ks++){
        bf16x8 af[2], bfr[4];
        #pragma unroll
        for (int mt=0;mt<2;mt++) af[mt]  = *(const bf16x8*)&As[w*32+mt*16+ll][ks*32+lg*8];
        #pragma unroll
        for (int nt=0;nt<4;nt++) bfr[nt] = *(const bf16x8*)&Bs[nt*16+ll][ks*32+lg*8];
        #pragma unroll
        for (int mt=0;mt<2;mt++)
            #pragma unroll
            for (int nt=0;nt<4;nt++)
                acc[mt][nt] = mfma16(af[mt], bfr[nt], acc[mt][nt]);
    }
    #pragma unroll
    for (int mt=0;mt<2;mt++){
        int g = ms*8 + w*2 + mt;
        float mean = stats[(b*32+g)*2];
        float rstd = stats[(b*32+g)*2+1];
        #pragma unroll
        for (int r=0;r<4;r++){
            int o = o0 + w*32 + mt*16 + lg*4 + r;
            float sw = rstd * gw[o];
            float sb = gb[o] - mean*sw;
            #pragma unroll
            for (int nt=0;nt<4;nt++){
                int hw = n0 + nt*16 + ll;
                size_t gi = (size_t)(b*512 + o)*32768 + hw;
                out[gi] = x[gi] + acc[mt][nt][r]*sw + sb;
            }
        }
    }
}

// ---------------------------------------------------------------------------
extern "C" void kernel_launch(void* const* d_in, const int* in_sizes, int n_in,
                              void* d_out, int out_size, void* d_ws, size_t ws_size,
                              hipStream_t stream)
{
    (void)in_sizes; (void)n_in; (void)out_size; (void)ws_size;
    const float* x   = (const float*)d_in[0];
    const float* wi  = (const float*)d_in[1];
    const float* tq  = (const float*)d_in[2];
    const float* tk  = (const float*)d_in[3];
    const float* tv  = (const float*)d_in[4];
    const float* tnw = (const float*)d_in[5];
    const float* tnb = (const float*)d_in[6];
    const float* fq  = (const float*)d_in[7];
    const float* fk  = (const float*)d_in[8];
    const float* fv  = (const float*)d_in[9];
    const float* fnw = (const float*)d_in[10];
    const float* fnb = (const float*)d_in[11];
    const float* wo  = (const float*)d_in[12];
    const float* gnw = (const float*)d_in[13];
    const float* gnb = (const float*)d_in[14];
    float* out = (float*)d_out;

    char* ws = (char*)d_ws;
    const size_t MB = (size_t)1 << 20;
    bf16* Z    = (bf16*)(ws);            // 32MB tokens (b,h,w), also reused as f_out
    bf16* QB   = (bf16*)(ws + 32*MB);    // 32MB
    bf16* KB   = (bf16*)(ws + 64*MB);    // 32MB
    bf16* VT   = (bf16*)(ws + 96*MB);    // 32MB (transposed V)
    bf16* TOUT = (bf16*)(ws + 128*MB);   // 32MB tokens (b,w,h)
    float* PART  = (float*)(ws + 32*MB); // reuses QB (dead by then), 512KB
    float* STATS = (float*)(ws + 33*MB); // 1KB

    k_proj_in<<<2048, 256, 0, stream>>>(x, wi, Z);
    k_qkv<<<2048, 256, 0, stream>>>(Z, tnw, tnb, tq, tk, tv, QB, KB, VT, 8);
    k_attn<256><<<2048, 256, 0, stream>>>(QB, KB, VT, Z, TOUT, 7);
    k_qkv<<<2048, 256, 0, stream>>>(TOUT, fnw, fnb, fq, fk, fv, QB, KB, VT, 7);
    k_attn<128><<<4096, 256, 0, stream>>>(QB, KB, VT, TOUT, Z, 8);
    k_gnsum<<<8192, 256, 0, stream>>>(Z, wo, PART);
    k_gnstat<<<128, 256, 0, stream>>>(PART, STATS);
    k_apply<<<8192, 256, 0, stream>>>(Z, wo, x, STATS, gnw, gnb, out);
}

// Round 2
// 529.884 us; speedup vs baseline: 1.1302x; 1.1302x over previous
//
#include <hip/hip_runtime.h>
#include <cstdint>

typedef __bf16 bf16;
typedef __attribute__((ext_vector_type(8))) __bf16 bf16x8;
typedef __attribute__((ext_vector_type(4))) __bf16 bf16x4;
typedef __attribute__((ext_vector_type(4))) float f32x4;

static __device__ __forceinline__ f32x4 mfma16(bf16x8 a, bf16x8 b, f32x4 c) {
    return __builtin_amdgcn_mfma_f32_16x16x32_bf16(a, b, c, 0, 0, 0);
}
static __device__ __forceinline__ bf16x4 cvt4(f32x4 v) {
    bf16x4 r; r[0]=(bf16)v[0]; r[1]=(bf16)v[1]; r[2]=(bf16)v[2]; r[3]=(bf16)v[3]; return r;
}

// ---------------------------------------------------------------------------
// K1: proj_in.  z_tok[(b,h,w)][o] = sum_c x[b,c,h,w] * Wi[o,c]   (bf16 out)
// ---------------------------------------------------------------------------
__global__ __launch_bounds__(256) void k_proj_in(
    const float* __restrict__ x, const float* __restrict__ Wi, bf16* __restrict__ z)
{
    __shared__ bf16 As[128][72];
    __shared__ bf16 Bs[64][72];
    const int tid = threadIdx.x;
    const int lane = tid & 63, w = tid >> 6;
    const int ll = lane & 15, lg = lane >> 4;
    const int b = blockIdx.x >> 9;
    const int n0 = (blockIdx.x & 511) * 64;
    const float* xb = x + (size_t)b * 512 * 32768;

    f32x4 acc[2][4];
    const f32x4 Z4 = {0.f,0.f,0.f,0.f};
    #pragma unroll
    for (int i=0;i<2;i++) { acc[i][0]=Z4; acc[i][1]=Z4; acc[i][2]=Z4; acc[i][3]=Z4; }

    for (int c0 = 0; c0 < 512; c0 += 64) {
        #pragma unroll
        for (int r = 0; r < 8; ++r) {
            int idx = r*256 + tid;
            int o = idx >> 4, cq = idx & 15;
            f32x4 v = *(const f32x4*)(Wi + (size_t)o*512 + c0 + cq*4);
            *(bf16x4*)&As[o][cq*4] = cvt4(v);
        }
        #pragma unroll
        for (int r = 0; r < 4; ++r) {
            int idx = r*256 + tid;
            int k = idx >> 4, nq = idx & 15;
            f32x4 v = *(const f32x4*)(xb + (size_t)(c0 + k)*32768 + n0 + nq*4);
            #pragma unroll
            for (int j=0;j<4;j++) Bs[nq*4+j][k] = (bf16)v[j];
        }
        __syncthreads();
        #pragma unroll
        for (int ks = 0; ks < 2; ++ks) {
            bf16x8 af[2], bfr[4];
            #pragma unroll
            for (int mt=0;mt<2;mt++) af[mt]  = *(const bf16x8*)&As[w*32+mt*16+ll][ks*32+lg*8];
            #pragma unroll
            for (int nt=0;nt<4;nt++) bfr[nt] = *(const bf16x8*)&Bs[nt*16+ll][ks*32+lg*8];
            #pragma unroll
            for (int mt=0;mt<2;mt++)
                #pragma unroll
                for (int nt=0;nt<4;nt++)
                    acc[mt][nt] = mfma16(af[mt], bfr[nt], acc[mt][nt]);
        }
        __syncthreads();
    }
    #pragma unroll
    for (int mt=0;mt<2;mt++)
      #pragma unroll
      for (int nt=0;nt<4;nt++) {
        int o0 = w*32 + mt*16 + lg*4;
        int token = b*32768 + n0 + nt*16 + ll;
        *(bf16x4*)&z[(size_t)token*128 + o0] = cvt4(acc[mt][nt]);
      }
}

// ---------------------------------------------------------------------------
// K2: fused LayerNorm + QKV projection. Scale log2(e)/sqrt(d) folded into Wq.
// ---------------------------------------------------------------------------
__global__ __launch_bounds__(256) void k_qkv(
    const bf16* __restrict__ zin, const float* __restrict__ lnw, const float* __restrict__ lnb,
    const float* __restrict__ Wq, const float* __restrict__ Wk, const float* __restrict__ Wv,
    bf16* __restrict__ Qb, bf16* __restrict__ Kb, bf16* __restrict__ Vt, int nshift)
{
    __shared__ bf16 xs[64][136];
    __shared__ bf16 wsm[128][136];
    const int tid = threadIdx.x;
    const int lane = tid & 63, w = tid >> 6;
    const int ll = lane & 15, lg = lane >> 4;
    const int t0 = blockIdx.x * 64;
    const int N = 1 << nshift;

    {
        const int sub = tid & 15;
        float wv[8], bv[8];
        #pragma unroll
        for (int j=0;j<8;j++){ wv[j]=lnw[sub*8+j]; bv[j]=lnb[sub*8+j]; }
        #pragma unroll
        for (int r=0;r<4;r++){
            int tl = r*16 + (tid >> 4);
            bf16x8 v = *(const bf16x8*)&zin[(size_t)(t0+tl)*128 + sub*8];
            float f[8]; float sm=0.f, ssq=0.f;
            #pragma unroll
            for (int j=0;j<8;j++){ f[j]=(float)v[j]; sm+=f[j]; ssq+=f[j]*f[j]; }
            #pragma unroll
            for (int d=1; d<16; d<<=1){ sm += __shfl_xor(sm,d); ssq += __shfl_xor(ssq,d); }
            float mean = sm*(1.f/128.f);
            float var  = ssq*(1.f/128.f) - mean*mean;
            float rr = rsqrtf(var + 1e-5f);
            bf16x8 ov;
            #pragma unroll
            for (int j=0;j<8;j++) ov[j] = (bf16)((f[j]-mean)*rr*wv[j] + bv[j]);
            *(bf16x8*)&xs[tl][sub*8] = ov;
        }
    }

    const float* Wm[3] = {Wq, Wk, Wv};
    const f32x4 Z4 = {0.f,0.f,0.f,0.f};
    for (int m = 0; m < 3; ++m) {
        __syncthreads();
        const float scale = (m == 0) ? 0.25503486f : 1.0f;  // log2(e)/sqrt(32)
        #pragma unroll
        for (int r=0;r<16;r++){
            int idx = r*256 + tid;
            int o = idx >> 5, q = idx & 31;
            f32x4 v = *(const f32x4*)(Wm[m] + (size_t)o*128 + q*4);
            v[0]*=scale; v[1]*=scale; v[2]*=scale; v[3]*=scale;
            *(bf16x4*)&wsm[o][q*4] = cvt4(v);
        }
        __syncthreads();
        f32x4 acc[4][2];
        #pragma unroll
        for (int i=0;i<4;i++){ acc[i][0]=Z4; acc[i][1]=Z4; }
        #pragma unroll
        for (int ks=0; ks<4; ++ks){
            bf16x8 xa[4], wb[2];
            #pragma unroll
            for (int tt=0;tt<4;tt++) xa[tt] = *(const bf16x8*)&xs[tt*16+ll][ks*32+lg*8];
            #pragma unroll
            for (int ot=0;ot<2;ot++) wb[ot] = *(const bf16x8*)&wsm[w*32+ot*16+ll][ks*32+lg*8];
            if (m < 2) {
                #pragma unroll
                for (int tt=0;tt<4;tt++)
                    #pragma unroll
                    for (int ot=0;ot<2;ot++)
                        acc[tt][ot] = mfma16(xa[tt], wb[ot], acc[tt][ot]);   // D[token][o]
            } else {
                #pragma unroll
                for (int tt=0;tt<4;tt++)
                    #pragma unroll
                    for (int ot=0;ot<2;ot++)
                        acc[tt][ot] = mfma16(wb[ot], xa[tt], acc[tt][ot]);   // D[o][token]
            }
        }
        if (m < 2) {
            bf16* dst = (m==0) ? Qb : Kb;
            #pragma unroll
            for (int tt=0;tt<4;tt++)
              #pragma unroll
              for (int ot=0;ot<2;ot++)
                #pragma unroll
                for (int r=0;r<4;r++){
                    int token = t0 + tt*16 + lg*4 + r;
                    int sq = token >> nshift, n = token & (N-1);
                    int dk = ot*16 + ll;
                    dst[((size_t)(sq*4 + w)*N + n)*32 + dk] = (bf16)acc[tt][ot][r];
                }
        } else {
            #pragma unroll
            for (int tt=0;tt<4;tt++)
              #pragma unroll
              for (int ot=0;ot<2;ot++)
                #pragma unroll
                for (int r=0;r<4;r++){
                    int dk = ot*16 + lg*4 + r;
                    int token = t0 + tt*16 + ll;
                    int sq = token >> nshift, n = token & (N-1);
                    Vt[((size_t)(sq*4 + w)*32 + dk)*N + n] = (bf16)acc[tt][ot][r];
                }
        }
    }
}

// ---------------------------------------------------------------------------
// K3: attention, non-flash. One wave = 16 queries, full score row in regs.
// K/V frags read direct from global (L2-resident). Exact one-shot softmax.
// P transposed through wave-private LDS. Residual + transpose fused in store.
// ---------------------------------------------------------------------------
template<int N>
__global__ __launch_bounds__(256) void k_attn(
    const bf16* __restrict__ Qb, const bf16* __restrict__ Kb, const bf16* __restrict__ Vt,
    const bf16* __restrict__ tin, bf16* __restrict__ tout, int spb_shift)
{
    constexpr int T = N / 16;        // key tiles of 16
    constexpr int PITCH = N + 8;     // row stride 2*(N+8) B == 16 mod 128 -> bank-spread
    __shared__ bf16 Ps[4][16][PITCH];
    const int tid = threadIdx.x;
    const int lane = tid & 63, w = tid >> 6;
    const int ll = lane & 15, lg = lane >> 4;
    const int qb = blockIdx.x & (N/64 - 1);
    const int sh = blockIdx.x / (N/64);
    const int s = sh >> 2, h = sh & 3;
    const size_t base = (size_t)sh * N * 32;
    const int q0 = qb*64 + w*16;

    // Q fragment: A-layout [q][d], lane ll = q row, lg*8 = d offset
    bf16x8 qf = *(const bf16x8*)&Qb[base + (size_t)(q0 + ll)*32 + lg*8];

    const f32x4 Z4 = {0.f,0.f,0.f,0.f};
    f32x4 sc[T];
    #pragma unroll
    for (int t=0;t<T;t++){
        bf16x8 kf = *(const bf16x8*)&Kb[base + (size_t)(t*16 + ll)*32 + lg*8];
        sc[t] = mfma16(qf, kf, Z4);   // D[q][key]: col ll=key, row lg*4+r=q (pre-scaled)
    }
    // exact softmax per query row (fixed lg,r; reduce over t regs then 16 ll lanes)
    f32x4 sum;
    #pragma unroll
    for (int r=0;r<4;r++){
        float m = sc[0][r];
        #pragma unroll
        for (int t=1;t<T;t++) m = fmaxf(m, sc[t][r]);
        #pragma unroll
        for (int d=1; d<16; d<<=1) m = fmaxf(m, __shfl_xor(m, d));
        float s_ = 0.f;
        #pragma unroll
        for (int t=0;t<T;t++){ float p = exp2f(sc[t][r] - m); sc[t][r] = p; s_ += p; }
        #pragma unroll
        for (int d=1; d<16; d<<=1) s_ += __shfl_xor(s_, d);
        sum[r] = s_;
    }
    // transpose P into A-layout via wave-private LDS (no barrier needed)
    #pragma unroll
    for (int t=0;t<T;t++)
        #pragma unroll
        for (int r=0;r<4;r++)
            Ps[w][lg*4+r][t*16+ll] = (bf16)sc[t][r];

    f32x4 O[2] = {Z4, Z4};
    #pragma unroll
    for (int ks=0; ks<N/32; ++ks){
        bf16x8 pf = *(const bf16x8*)&Ps[w][ll][ks*32 + lg*8];       // A[q=ll][key]
        bf16x8 v0 = *(const bf16x8*)&Vt[base + (size_t)ll*N      + ks*32 + lg*8];  // B[dout=ll][key]
        bf16x8 v1 = *(const bf16x8*)&Vt[base + (size_t)(16+ll)*N + ks*32 + lg*8];
        O[0] = mfma16(pf, v0, O[0]);
        O[1] = mfma16(pf, v1, O[1]);
    }
    const int spb_mask = (1 << spb_shift) - 1;
    #pragma unroll
    for (int r=0;r<4;r++){
        float inv = 1.f / sum[r];
        int q = q0 + lg*4 + r;
        size_t ti = ((size_t)(s*N + q))*128 + h*32;
        size_t to = ((size_t)((((s >> spb_shift)*N + q) << spb_shift) + (s & spb_mask)))*128 + h*32;
        #pragma unroll
        for (int dt=0; dt<2; ++dt){
            int dout = dt*16 + ll;
            float val = O[dt][r]*inv + (float)tin[ti + dout];
            tout[to + dout] = (bf16)val;
        }
    }
}

// ---------------------------------------------------------------------------
// K4a: proj_out GEMM, partial GroupNorm sums only.
// ---------------------------------------------------------------------------
__global__ __launch_bounds__(256) void k_gnsum(
    const bf16* __restrict__ f, const float* __restrict__ Wo, float* __restrict__ part)
{
    __shared__ bf16 As[128][136];
    __shared__ bf16 Bs[64][136];
    const int tid = threadIdx.x;
    const int lane = tid & 63, w = tid >> 6;
    const int ll = lane & 15, lg = lane >> 4;
    const int b  = blockIdx.x >> 11;
    const int ms = (blockIdx.x >> 9) & 3;
    const int ns = blockIdx.x & 511;
    const int n0 = ns*64, o0 = ms*128;

    #pragma unroll
    for (int r=0;r<16;r++){
        int idx = r*256 + tid;
        int o = idx >> 5, q = idx & 31;
        f32x4 v = *(const f32x4*)(Wo + (size_t)(o0+o)*128 + q*4);
        *(bf16x4*)&As[o][q*4] = cvt4(v);
    }
    #pragma unroll
    for (int r=0;r<4;r++){
        int idx = r*256 + tid;
        int nl = idx >> 4, ch = idx & 15;
        *(bf16x8*)&Bs[nl][ch*8] = *(const bf16x8*)&f[(size_t)(b*32768 + n0 + nl)*128 + ch*8];
    }
    __syncthreads();
    const f32x4 Z4 = {0.f,0.f,0.f,0.f};
    f32x4 acc[2][4];
    #pragma unroll
    for (int i=0;i<2;i++){ acc[i][0]=Z4; acc[i][1]=Z4; acc[i][2]=Z4; acc[i][3]=Z4; }
    #pragma unroll
    for (int ks=0;ks<4;ks++){
        bf16x8 af[2], bfr[4];
        #pragma unroll
        for (int mt=0;mt<2;mt++) af[mt]  = *(const bf16x8*)&As[w*32+mt*16+ll][ks*32+lg*8];
        #pragma unroll
        for (int nt=0;nt<4;nt++) bfr[nt] = *(const bf16x8*)&Bs[nt*16+ll][ks*32+lg*8];
        #pragma unroll
        for (int mt=0;mt<2;mt++)
            #pragma unroll
            for (int nt=0;nt<4;nt++)
                acc[mt][nt] = mfma16(af[mt], bfr[nt], acc[mt][nt]);
    }
    #pragma unroll
    for (int mt=0;mt<2;mt++){
        float ps=0.f, pss=0.f;
        #pragma unroll
        for (int nt=0;nt<4;nt++)
            #pragma unroll
            for (int r=0;r<4;r++){ float v = acc[mt][nt][r]; ps += v; pss += v*v; }
        #pragma unroll
        for (int d=1; d<64; d<<=1){ ps += __shfl_xor(ps,d); pss += __shfl_xor(pss,d); }
        if (lane == 0){
            int g = ms*8 + w*2 + mt;
            size_t pi = ((size_t)(b*32+g)*512 + ns)*2;
            part[pi] = ps; part[pi+1] = pss;
        }
    }
}

__global__ __launch_bounds__(256) void k_gnstat(
    const float* __restrict__ part, float* __restrict__ stats)
{
    const int bg = blockIdx.x;
    float s = 0.f, ss = 0.f;
    for (int i = threadIdx.x; i < 512; i += 256) {
        s  += part[((size_t)bg*512 + i)*2];
        ss += part[((size_t)bg*512 + i)*2 + 1];
    }
    #pragma unroll
    for (int d=1; d<64; d<<=1){ s += __shfl_xor(s,d); ss += __shfl_xor(ss,d); }
    __shared__ float sh[8];
    const int w = threadIdx.x >> 6;
    if ((threadIdx.x & 63) == 0) { sh[w*2] = s; sh[w*2+1] = ss; }
    __syncthreads();
    if (threadIdx.x == 0) {
        float S = sh[0]+sh[2]+sh[4]+sh[6], SS = sh[1]+sh[3]+sh[5]+sh[7];
        float mean = S * (1.f/524288.f);
        float var  = SS * (1.f/524288.f) - mean*mean;
        stats[bg*2]   = mean;
        stats[bg*2+1] = rsqrtf(var + 1e-5f);
    }
}

// ---------------------------------------------------------------------------
// K5: proj_out GEMM again + GroupNorm apply + residual + fp32 store.
// ---------------------------------------------------------------------------
__global__ __launch_bounds__(256) void k_apply(
    const bf16* __restrict__ f, const float* __restrict__ Wo, const float* __restrict__ x,
    const float* __restrict__ stats, const float* __restrict__ gw, const float* __restrict__ gb,
    float* __restrict__ out)
{
    __shared__ bf16 As[128][136];
    __shared__ bf16 Bs[64][136];
    const int tid = threadIdx.x;
    const int lane = tid & 63, w = tid >> 6;
    const int ll = lane & 15, lg = lane >> 4;
    const int b  = blockIdx.x >> 11;
    const int ms = (blockIdx.x >> 9) & 3;
    const int ns = blockIdx.x & 511;
    const int n0 = ns*64, o0 = ms*128;

    #pragma unroll
    for (int r=0;r<16;r++){
        int idx = r*256 + tid;
        int o = idx >> 5, q = idx & 31;
        f32x4 v = *(const f32x4*)(Wo + (size_t)(o0+o)*128 + q*4);
        *(bf16x4*)&As[o][q*4] = cvt4(v);
    }
    #pragma unroll
    for (int r=0;r<4;r++){
        int idx = r*256 + tid;
        int nl = idx >> 4, ch = idx & 15;
        *(bf16x8*)&Bs[nl][ch*8] = *(const bf16x8*)&f[(size_t)(b*32768 + n0 + nl)*128 + ch*8];
    }
    __syncthreads();
    const f32x4 Z4 = {0.f,0.f,0.f,0.f};
    f32x4 acc[2][4];
    #pragma unroll
    for (int i=0;i<2;i++){ acc[i][0]=Z4; acc[i][1]=Z4; acc[i][2]=Z4; acc[i][3]=Z4; }
    #pragma unroll
    for (int ks=0;ks<4;ks++){
        bf16x8 af[2], bfr[4];
        #pragma unroll
        for (int mt=0;mt<2;mt++) af[mt]  = *(const bf16x8*)&As[w*32+mt*16+ll][ks*32+lg*8];
        #pragma unroll
        for (int nt=0;nt<4;nt++) bfr[nt] = *(const bf16x8*)&Bs[nt*16+ll][ks*32+lg*8];
        #pragma unroll
        for (int mt=0;mt<2;mt++)
            #pragma unroll
            for (int nt=0;nt<4;nt++)
                acc[mt][nt] = mfma16(af[mt], bfr[nt], acc[mt][nt]);
    }
    #pragma unroll
    for (int mt=0;mt<2;mt++){
        int g = ms*8 + w*2 + mt;
        float mean = stats[(b*32+g)*2];
        float rstd = stats[(b*32+g)*2+1];
        #pragma unroll
        for (int r=0;r<4;r++){
            int o = o0 + w*32 + mt*16 + lg*4 + r;
            float sw = rstd * gw[o];
            float sb = gb[o] - mean*sw;
            #pragma unroll
            for (int nt=0;nt<4;nt++){
                int hw = n0 + nt*16 + ll;
                size_t gi = (size_t)(b*512 + o)*32768 + hw;
                out[gi] = x[gi] + acc[mt][nt][r]*sw + sb;
            }
        }
    }
}

// ---------------------------------------------------------------------------
extern "C" void kernel_launch(void* const* d_in, const int* in_sizes, int n_in,
                              void* d_out, int out_size, void* d_ws, size_t ws_size,
                              hipStream_t stream)
{
    (void)in_sizes; (void)n_in; (void)out_size; (void)ws_size;
    const float* x   = (const float*)d_in[0];
    const float* wi  = (const float*)d_in[1];
    const float* tq  = (const float*)d_in[2];
    const float* tk  = (const float*)d_in[3];
    const float* tv  = (const float*)d_in[4];
    const float* tnw = (const float*)d_in[5];
    const float* tnb = (const float*)d_in[6];
    const float* fq  = (const float*)d_in[7];
    const float* fk  = (const float*)d_in[8];
    const float* fv  = (const float*)d_in[9];
    const float* fnw = (const float*)d_in[10];
    const float* fnb = (const float*)d_in[11];
    const float* wo  = (const float*)d_in[12];
    const float* gnw = (const float*)d_in[13];
    const float* gnb = (const float*)d_in[14];
    float* out = (float*)d_out;

    char* ws = (char*)d_ws;
    const size_t MB = (size_t)1 << 20;
    bf16* Z    = (bf16*)(ws);            // 32MB tokens (b,h,w), reused as f_out
    bf16* QB   = (bf16*)(ws + 32*MB);    // 32MB
    bf16* KB   = (bf16*)(ws + 64*MB);    // 32MB
    bf16* VT   = (bf16*)(ws + 96*MB);    // 32MB (transposed V)
    bf16* TOUT = (bf16*)(ws + 128*MB);   // 32MB tokens (b,w,h)
    float* PART  = (float*)(ws + 32*MB); // reuses QB (dead by then)
    float* STATS = (float*)(ws + 33*MB);

    k_proj_in<<<2048, 256, 0, stream>>>(x, wi, Z);
    k_qkv<<<2048, 256, 0, stream>>>(Z, tnw, tnb, tq, tk, tv, QB, KB, VT, 8);
    k_attn<256><<<8192, 256, 0, stream>>>(QB, KB, VT, Z, TOUT, 7);
    k_qkv<<<2048, 256, 0, stream>>>(TOUT, fnw, fnb, fq, fk, fv, QB, KB, VT, 7);
    k_attn<128><<<8192, 256, 0, stream>>>(QB, KB, VT, TOUT, Z, 8);
    k_gnsum<<<8192, 256, 0, stream>>>(Z, wo, PART);
    k_gnstat<<<128, 256, 0, stream>>>(PART, STATS);
    k_apply<<<8192, 256, 0, stream>>>(Z, wo, x, STATS, gnw, gnb, out);
}